// Round 7
// baseline (217.940 us; speedup 1.0000x reference)
//
#include <hip/hip_runtime.h>
#include <hip/hip_bf16.h>

#define NROW 8192
#define FINC 256
#define FOUTC 256
#define BM 32
#define BK 64
#define NT (NROW / BK)   // 128

typedef __attribute__((ext_vector_type(8))) short bf16x8;
typedef __attribute__((ext_vector_type(4))) float f32x4;

__device__ __forceinline__ unsigned short f2bf(float f) {
  unsigned u = __float_as_uint(f);
  u += 0x7fffu + ((u >> 16) & 1u);   // round-to-nearest-even
  return (unsigned short)(u >> 16);
}
__device__ __forceinline__ float bf2f(unsigned short h) {
  return __uint_as_float(((unsigned)h) << 16);
}

// ---- kernel 1 (new): fused rowsum + bf16 convert + GEMM-tile reorder ----
// adj_t layout: [mtile 256][kt 128][row 32][k 64] bf16, with each row's 16-B
// groups XOR-swizzled: logical kbyte Y stored at Y ^ ((row&7)<<4). GEMM then
// global_load_lds's each 4-KB tile CONTIGUOUSLY (DRAM-friendly) and ds_reads
// with the same XOR (bank-conflict-free).
__global__ __launch_bounds__(1024) void prep_kernel(const float* __restrict__ adj,
                                                    float* __restrict__ D,
                                                    unsigned short* __restrict__ adjt) {
  __shared__ unsigned short lds[32][1032];   // 1024 cols + 8 pad elems (stride 2064 B)
  const int t = threadIdx.x;
  const int m = blockIdx.x;
  const int r = t >> 5;        // 0..31 row (read phase)
  const int ph = t & 31;       // col phase (read phase)
  const int slot = t & 511;
  const int wt = slot >> 5;    // 0..15 tile (write phase)
  const int wr = slot & 31;    // 0..31 row  (write phase)
  const int jh = t >> 9;       // 0/1 j-half (write phase)
  float sum = 0.f;
  const float* src0 = adj + (size_t)(m * 32 + r) * NROW + ph * 4;
  unsigned short* dst0 = adjt + ((size_t)m * 128 + wt) * 2048 + wr * 64;

  for (int c = 0; c < 8; ++c) {
    const float* src = src0 + c * 1024;
#pragma unroll
    for (int j = 0; j < 8; ++j) {
      float4 v = *reinterpret_cast<const float4*>(src + j * 128);
      sum += (v.x + v.y) + (v.z + v.w);
      ushort4 b;
      b.x = f2bf(v.x); b.y = f2bf(v.y); b.z = f2bf(v.z); b.w = f2bf(v.w);
      *reinterpret_cast<ushort4*>(&lds[r][j * 128 + ph * 4]) = b;
    }
    __syncthreads();
    unsigned short* dst = dst0 + (size_t)c * 16 * 2048;
#pragma unroll
    for (int jj = 0; jj < 4; ++jj) {
      const int j = jh * 4 + jj;
      bf16x8 v = *reinterpret_cast<const bf16x8*>((const char*)&lds[wr][0] + wt * 128 + j * 16);
      *reinterpret_cast<bf16x8*>((char*)dst + ((j * 16) ^ ((wr & 7) << 4))) = v;
    }
    __syncthreads();
  }
  // row sums: 32 threads (ph) per row, all within one 32-lane half of a wave
  sum += __shfl_xor(sum, 1, 64);
  sum += __shfl_xor(sum, 2, 64);
  sum += __shfl_xor(sum, 4, 64);
  sum += __shfl_xor(sum, 8, 64);
  sum += __shfl_xor(sum, 16, 64);
  if (ph == 0) D[m * 32 + r] = rsqrtf(sum + 1.0f);
}

// ---- kernel 2: s2T[f][j] = bf16( D[j] * (x @ W)[j][f] ) ----
__global__ __launch_bounds__(256) void support_kernel(const float* __restrict__ x,
                                                      const float* __restrict__ W,
                                                      const float* __restrict__ D,
                                                      unsigned short* __restrict__ s2T) {
  __shared__ float xs[32][FINC];
  const int t = threadIdx.x;
  const int r0 = blockIdx.x * 32;
  {
    const float4* xg = reinterpret_cast<const float4*>(x + (size_t)r0 * FINC);
    float4* xl = reinterpret_cast<float4*>(&xs[0][0]);
#pragma unroll
    for (int i = 0; i < 8; ++i) xl[t + i * 256] = xg[t + i * 256];
  }
  __syncthreads();
  const int w = t >> 6, l = t & 63;
  float acc[8][4] = {};
  const float4* W4 = reinterpret_cast<const float4*>(W);
#pragma unroll 4
  for (int k = 0; k < FINC; ++k) {
    float4 wv = W4[k * 64 + l];
#pragma unroll
    for (int m = 0; m < 8; ++m) {
      float xv = xs[w * 8 + m][k];
      acc[m][0] = fmaf(xv, wv.x, acc[m][0]);
      acc[m][1] = fmaf(xv, wv.y, acc[m][1]);
      acc[m][2] = fmaf(xv, wv.z, acc[m][2]);
      acc[m][3] = fmaf(xv, wv.w, acc[m][3]);
    }
  }
#pragma unroll
  for (int m = 0; m < 8; ++m) {
    const int j = r0 + w * 8 + m;
    const float d = D[j];
    const int f0 = l * 4;
#pragma unroll
    for (int q = 0; q < 4; ++q)
      s2T[(size_t)(f0 + q) * NROW + j] = f2bf(d * acc[m][q]);
  }
}

// ---- kernel 3 (new): GEMM with tiled-bf16 A via global_load_lds ----
__global__ __launch_bounds__(512) void gcn_gemm_kernel(const unsigned short* __restrict__ adjt,
                                                       const unsigned short* __restrict__ s2T,
                                                       const float* __restrict__ D,
                                                       const float* __restrict__ bias,
                                                       float* __restrict__ out) {
  __shared__ __align__(16) unsigned short As[3][BM * BK];      // 3 x 4 KB, pre-swizzled
  __shared__ __align__(16) unsigned short Bs[3][FOUTC * BK];   // 3 x 32 KB, swizzled

  const int t = threadIdx.x, wid = t >> 6, l = t & 63;
  const int bm0 = blockIdx.x * BM;

  // B staging: lane l -> row c*8+(l>>3), pre-swizzled source kbyte
  const int bn = l >> 3;
  const unsigned bks = (unsigned)(((l & 7) * 16) ^ (bn << 4));

  f32x4 acc[2][2] = {};

  const unsigned swz = (unsigned)((l & 7) << 4);
  const int fr = l & 15;
  const unsigned kb = (unsigned)((l >> 4) * 16);
  const int nb = wid * 32;

  const unsigned short* atile0 = adjt + (size_t)blockIdx.x * 128 * 2048;

  // stage = 2 x A(size-4) + 4 x B(size-16) = 6 vmem ops per wave, uniform
  auto stage = [&](int kt, int sl) {
    const char* tile = (const char*)(atile0 + (size_t)kt * 2048);
#pragma unroll
    for (int i = 0; i < 2; ++i) {
      const int q = wid * 2 + i;   // 16 chunks of 256 B
      __builtin_amdgcn_global_load_lds(
          (const __attribute__((address_space(1))) unsigned int*)(tile + q * 256 + l * 4),
          (__attribute__((address_space(3))) unsigned int*)((char*)&As[sl][0] + q * 256),
          4, 0, 0);
    }
#pragma unroll
    for (int i = 0; i < 4; ++i) {
      const int c = wid * 4 + i;
      const int n = c * 8 + bn;
      const unsigned short* src = s2T + (size_t)n * NROW + (size_t)kt * BK;
      __builtin_amdgcn_global_load_lds(
          (const __attribute__((address_space(1))) unsigned int*)((const char*)src + bks),
          (__attribute__((address_space(3))) unsigned int*)((char*)&Bs[sl][0] + c * 1024),
          16, 0, 0);
    }
  };
  auto compute = [&](int sl) {
    const char* Ab = (const char*)&As[sl][0];
    const char* Bb = (const char*)&Bs[sl][0];
#pragma unroll
    for (int kk = 0; kk < 2; ++kk) {
      const unsigned kx = ((unsigned)(kk * 64) + kb) ^ swz;
      bf16x8 a0 = *reinterpret_cast<const bf16x8*>(Ab + fr * 128 + kx);
      bf16x8 a1 = *reinterpret_cast<const bf16x8*>(Ab + (fr + 16) * 128 + kx);
      bf16x8 b0 = *reinterpret_cast<const bf16x8*>(Bb + (nb + fr) * 128 + kx);
      bf16x8 b1 = *reinterpret_cast<const bf16x8*>(Bb + (nb + 16 + fr) * 128 + kx);
      acc[0][0] = __builtin_amdgcn_mfma_f32_16x16x32_bf16(a0, b0, acc[0][0], 0, 0, 0);
      acc[0][1] = __builtin_amdgcn_mfma_f32_16x16x32_bf16(a0, b1, acc[0][1], 0, 0, 0);
      acc[1][0] = __builtin_amdgcn_mfma_f32_16x16x32_bf16(a1, b0, acc[1][0], 0, 0, 0);
      acc[1][1] = __builtin_amdgcn_mfma_f32_16x16x32_bf16(a1, b1, acc[1][1], 0, 0, 0);
    }
  };

  // prologue: windows W0, W1 (6 ops each, fenced for exact vmcnt accounting)
  stage(0, 0);
  asm volatile("" ::: "memory");
  stage(1, 1);

  // main loop: at top of kt, wait vmcnt(6) -> W_kt complete (W_{kt+1} in flight)
#define PIPE_ITER(KT, S0, S2)                                                  \
  asm volatile("s_waitcnt vmcnt(6) lgkmcnt(0)\n\ts_barrier" ::: "memory");     \
  stage((KT) + 2, S2);                                                         \
  compute(S0);

#pragma unroll 1
  for (int kt = 0; kt < NT - 2; kt += 3) {
    PIPE_ITER(kt + 0, 0, 2)
    PIPE_ITER(kt + 1, 1, 0)
    PIPE_ITER(kt + 2, 2, 1)
  }
#undef PIPE_ITER

  // kt = NT-2 (slot 0): W_{NT-1} in flight
  asm volatile("s_waitcnt vmcnt(6) lgkmcnt(0)\n\ts_barrier" ::: "memory");
  compute(0);
  // kt = NT-1 (slot 1): drain
  asm volatile("s_waitcnt vmcnt(0) lgkmcnt(0)\n\ts_barrier" ::: "memory");
  compute(1);

  // epilogue: C/D layout col = l&15, row = (l>>4)*4 + q
#pragma unroll
  for (int m = 0; m < 2; ++m) {
#pragma unroll
    for (int n = 0; n < 2; ++n) {
#pragma unroll
      for (int q = 0; q < 4; ++q) {
        const int i = bm0 + m * 16 + (l >> 4) * 4 + q;
        const int f = wid * 32 + n * 16 + fr;
        const float selfv = bf2f(s2T[(size_t)f * NROW + i]);
        float v = (acc[m][n][q] + selfv) * D[i] + bias[f];
        out[(size_t)i * FOUTC + f] = fmaxf(v, 0.0f);
      }
    }
  }
}

// ================= fallback path (round-3, used if ws too small) =============
__global__ __launch_bounds__(256) void rowsum_kernel(const float* __restrict__ adj,
                                                     float* __restrict__ D) {
  const int row = blockIdx.x * 4 + (threadIdx.x >> 6);
  const int l = threadIdx.x & 63;
  const float4* p = reinterpret_cast<const float4*>(adj + (size_t)row * NROW);
  float s0 = 0.f, s1 = 0.f, s2 = 0.f, s3 = 0.f;
#pragma unroll
  for (int i = 0; i < 8; ++i) {
    float4 a = p[l + (i * 4 + 0) * 64];
    float4 b = p[l + (i * 4 + 1) * 64];
    float4 c = p[l + (i * 4 + 2) * 64];
    float4 d = p[l + (i * 4 + 3) * 64];
    s0 += (a.x + a.y) + (a.z + a.w);
    s1 += (b.x + b.y) + (b.z + b.w);
    s2 += (c.x + c.y) + (c.z + c.w);
    s3 += (d.x + d.y) + (d.z + d.w);
  }
  float s = (s0 + s1) + (s2 + s3);
#pragma unroll
  for (int off = 32; off > 0; off >>= 1) s += __shfl_down(s, off, 64);
  if (l == 0) D[row] = 1.0f / sqrtf(s + 1.0f);
}

__global__ __launch_bounds__(512) void gemm_fb(const float* __restrict__ adj,
                                               const unsigned short* __restrict__ s2T,
                                               const float* __restrict__ D,
                                               const float* __restrict__ bias,
                                               float* __restrict__ out) {
  __shared__ __align__(16) unsigned short As[3][BM * BK];
  __shared__ __align__(16) unsigned short Bs[3][FOUTC * BK];
  const int t = threadIdx.x, wid = t >> 6, l = t & 63;
  const int bm0 = blockIdx.x * BM;
  const int ar = t >> 4;
  const unsigned awoff = (unsigned)(ar * 128 + (((t & 15) * 8) ^ ((ar & 7) << 4)));
  const float4* arow = reinterpret_cast<const float4*>(adj + (size_t)(bm0 + ar) * NROW) + (t & 15);
  const int bn = l >> 3;
  const unsigned bks = (unsigned)(((l & 7) * 16) ^ (bn << 4));
  f32x4 acc[2][2] = {};
  const unsigned swz = (unsigned)((l & 7) << 4);
  const int fr = l & 15;
  const unsigned kb = (unsigned)((l >> 4) * 16);
  const int nb = wid * 32;
  auto stageB = [&](int kt, int sl) {
#pragma unroll
    for (int i = 0; i < 4; ++i) {
      const int c = wid * 4 + i;
      const int n = c * 8 + bn;
      const unsigned short* src = s2T + (size_t)n * NROW + (size_t)kt * BK;
      __builtin_amdgcn_global_load_lds(
          (const __attribute__((address_space(1))) unsigned int*)((const char*)src + bks),
          (__attribute__((address_space(3))) unsigned int*)((char*)&Bs[sl][0] + c * 1024),
          16, 0, 0);
    }
  };
  auto writeA = [&](float4 av, int sl) {
    ushort4 ab;
    ab.x = f2bf(av.x); ab.y = f2bf(av.y); ab.z = f2bf(av.z); ab.w = f2bf(av.w);
    *reinterpret_cast<ushort4*>((char*)&As[sl][0] + awoff) = ab;
  };
  auto compute = [&](int sl) {
    const char* Ab = (const char*)&As[sl][0];
    const char* Bb = (const char*)&Bs[sl][0];
#pragma unroll
    for (int kk = 0; kk < 2; ++kk) {
      const unsigned kx = ((unsigned)(kk * 64) + kb) ^ swz;
      bf16x8 a0 = *reinterpret_cast<const bf16x8*>(Ab + fr * 128 + kx);
      bf16x8 a1 = *reinterpret_cast<const bf16x8*>(Ab + (fr + 16) * 128 + kx);
      bf16x8 b0 = *reinterpret_cast<const bf16x8*>(Bb + (nb + fr) * 128 + kx);
      bf16x8 b1 = *reinterpret_cast<const bf16x8*>(Bb + (nb + 16 + fr) * 128 + kx);
      acc[0][0] = __builtin_amdgcn_mfma_f32_16x16x32_bf16(a0, b0, acc[0][0], 0, 0, 0);
      acc[0][1] = __builtin_amdgcn_mfma_f32_16x16x32_bf16(a0, b1, acc[0][1], 0, 0, 0);
      acc[1][0] = __builtin_amdgcn_mfma_f32_16x16x32_bf16(a1, b0, acc[1][0], 0, 0, 0);
      acc[1][1] = __builtin_amdgcn_mfma_f32_16x16x32_bf16(a1, b1, acc[1][1], 0, 0, 0);
    }
  };
  float4 a0p, a1p, a2p;
  {
    float4 a0v = arow[0];
    asm volatile("" ::: "memory");
    stageB(0, 0);
    a1p = arow[16];
    asm volatile("" ::: "memory");
    stageB(1, 1);
    a2p = arow[32];
    asm volatile("s_waitcnt vmcnt(10)" ::: "memory");
    writeA(a0v, 0);
  }
#define PIPE_ITER(KT, S0, S1, S2, AW, AN)                                      \
  asm volatile("s_waitcnt vmcnt(5) lgkmcnt(0)\n\ts_barrier" ::: "memory");     \
  writeA(AW, S1);                                                              \
  stageB((KT) + 2, S2);                                                        \
  if ((KT) < NT - 3) AN = arow[((KT) + 3) * 16];                               \
  compute(S0);
#pragma unroll 1
  for (int kt = 0; kt < NT - 2; kt += 3) {
    PIPE_ITER(kt + 0, 0, 1, 2, a1p, a0p)
    PIPE_ITER(kt + 1, 1, 2, 0, a2p, a1p)
    PIPE_ITER(kt + 2, 2, 0, 1, a0p, a2p)
  }
#undef PIPE_ITER
  asm volatile("s_waitcnt vmcnt(4) lgkmcnt(0)\n\ts_barrier" ::: "memory");
  writeA(a1p, 1);
  compute(0);
  asm volatile("s_waitcnt vmcnt(0) lgkmcnt(0)\n\ts_barrier" ::: "memory");
  compute(1);
#pragma unroll
  for (int m = 0; m < 2; ++m) {
#pragma unroll
    for (int n = 0; n < 2; ++n) {
#pragma unroll
      for (int q = 0; q < 4; ++q) {
        const int i = bm0 + m * 16 + (l >> 4) * 4 + q;
        const int f = wid * 32 + n * 16 + fr;
        const float selfv = bf2f(s2T[(size_t)f * NROW + i]);
        float v = (acc[m][n][q] + selfv) * D[i] + bias[f];
        out[(size_t)i * FOUTC + f] = fmaxf(v, 0.0f);
      }
    }
  }
}

extern "C" void kernel_launch(void* const* d_in, const int* in_sizes, int n_in,
                              void* d_out, int out_size, void* d_ws, size_t ws_size,
                              hipStream_t stream) {
  const float* x   = (const float*)d_in[0];
  const float* adj = (const float*)d_in[1];
  const float* W   = (const float*)d_in[2];
  const float* b   = (const float*)d_in[3];
  float* out = (float*)d_out;

  float* D = (float*)d_ws;                                                       // 32 KB
  unsigned short* s2T  = (unsigned short*)((char*)d_ws + 32768);                 // 4 MB
  unsigned short* adjt = (unsigned short*)((char*)d_ws + 32768 + 4194304);       // 128 MB

  const size_t need = 32768ull + 4194304ull + (size_t)NROW * NROW * 2ull;
  if (ws_size >= need) {
    prep_kernel<<<NROW / 32, 1024, 0, stream>>>(adj, D, adjt);
    support_kernel<<<NROW / 32, 256, 0, stream>>>(x, W, D, s2T);
    gcn_gemm_kernel<<<NROW / BM, 512, 0, stream>>>(adjt, s2T, D, b, out);
  } else {
    rowsum_kernel<<<NROW / 4, 256, 0, stream>>>(adj, D);
    support_kernel<<<NROW / 32, 256, 0, stream>>>(x, W, D, s2T);
    gemm_fb<<<NROW / BM, 512, 0, stream>>>(adj, s2T, D, b, out);
  }
}

// Round 8
// 163.154 us; speedup vs baseline: 1.3358x; 1.3358x over previous
//
#include <hip/hip_runtime.h>
#include <hip/hip_bf16.h>

#define NROW 8192
#define FINC 256
#define FOUTC 256
#define BM 64
#define BK 64
#define KSPLIT 4
#define KLOC (NROW / KSPLIT)   // 2048
#define NTL (KLOC / BK)        // 32 K-steps per block

typedef __attribute__((ext_vector_type(8))) short bf16x8;
typedef __attribute__((ext_vector_type(4))) float f32x4;

__device__ __forceinline__ unsigned short f2bf(float f) {
  unsigned u = __float_as_uint(f);
  u += 0x7fffu + ((u >> 16) & 1u);   // round-to-nearest-even
  return (unsigned short)(u >> 16);
}
__device__ __forceinline__ float bf2f(unsigned short h) {
  return __uint_as_float(((unsigned)h) << 16);
}

// ---- kernel 1: D[i] = 1/sqrt(1 + sum_j adj[i][j]); one wave per row ----
__global__ __launch_bounds__(256) void rowsum_kernel(const float* __restrict__ adj,
                                                     float* __restrict__ D) {
  const int row = blockIdx.x * 4 + (threadIdx.x >> 6);
  const int l = threadIdx.x & 63;
  const float4* p = reinterpret_cast<const float4*>(adj + (size_t)row * NROW);
  float s0 = 0.f, s1 = 0.f, s2 = 0.f, s3 = 0.f;
#pragma unroll
  for (int i = 0; i < 8; ++i) {
    float4 a = p[l + (i * 4 + 0) * 64];
    float4 b = p[l + (i * 4 + 1) * 64];
    float4 c = p[l + (i * 4 + 2) * 64];
    float4 d = p[l + (i * 4 + 3) * 64];
    s0 += (a.x + a.y) + (a.z + a.w);
    s1 += (b.x + b.y) + (b.z + b.w);
    s2 += (c.x + c.y) + (c.z + c.w);
    s3 += (d.x + d.y) + (d.z + d.w);
  }
  float s = (s0 + s1) + (s2 + s3);
#pragma unroll
  for (int off = 32; off > 0; off >>= 1) s += __shfl_down(s, off, 64);
  if (l == 0) D[row] = 1.0f / sqrtf(s + 1.0f);
}

// ---- kernel 2: s2T[f][j] = s2R[j][f] = bf16( D[j] * (x @ W)[j][f] ) ----
__global__ __launch_bounds__(256) void support_kernel(const float* __restrict__ x,
                                                      const float* __restrict__ W,
                                                      const float* __restrict__ D,
                                                      unsigned short* __restrict__ s2T,
                                                      unsigned short* __restrict__ s2R) {
  __shared__ float xs[32][FINC];
  const int t = threadIdx.x;
  const int r0 = blockIdx.x * 32;
  {
    const float4* xg = reinterpret_cast<const float4*>(x + (size_t)r0 * FINC);
    float4* xl = reinterpret_cast<float4*>(&xs[0][0]);
#pragma unroll
    for (int i = 0; i < 8; ++i) xl[t + i * 256] = xg[t + i * 256];
  }
  __syncthreads();
  const int w = t >> 6, l = t & 63;
  float acc[8][4] = {};
  const float4* W4 = reinterpret_cast<const float4*>(W);
#pragma unroll 4
  for (int k = 0; k < FINC; ++k) {
    float4 wv = W4[k * 64 + l];
#pragma unroll
    for (int m = 0; m < 8; ++m) {
      float xv = xs[w * 8 + m][k];
      acc[m][0] = fmaf(xv, wv.x, acc[m][0]);
      acc[m][1] = fmaf(xv, wv.y, acc[m][1]);
      acc[m][2] = fmaf(xv, wv.z, acc[m][2]);
      acc[m][3] = fmaf(xv, wv.w, acc[m][3]);
    }
  }
#pragma unroll
  for (int m = 0; m < 8; ++m) {
    const int j = r0 + w * 8 + m;
    const float d = D[j];
    const int f0 = l * 4;
    ushort4 rv;
    rv.x = f2bf(d * acc[m][0]);
    rv.y = f2bf(d * acc[m][1]);
    rv.z = f2bf(d * acc[m][2]);
    rv.w = f2bf(d * acc[m][3]);
    *reinterpret_cast<ushort4*>(&s2R[(size_t)j * FOUTC + f0]) = rv;
    s2T[(size_t)(f0 + 0) * NROW + j] = rv.x;
    s2T[(size_t)(f0 + 1) * NROW + j] = rv.y;
    s2T[(size_t)(f0 + 2) * NROW + j] = rv.z;
    s2T[(size_t)(f0 + 3) * NROW + j] = rv.w;
  }
}

// ---- kernel 3: K-split GEMM. part[ks][i][f] = sum_{j in K-slice ks} adj[i][j]*s2T[f][j]
// BM=64 x BN=256 x BK=64, 512 thr (8 waves as 2M x 4N), 2-slot LDS (80 KB ->
// 2 blocks/CU), counted vmcnt (never drains in main loop).
__global__ __launch_bounds__(512) void gcn_gemm_kernel(const float* __restrict__ adj,
                                                       const unsigned short* __restrict__ s2T,
                                                       float* __restrict__ part) {
  __shared__ __align__(16) unsigned short As[2][BM * BK];      // 2 x 8 KB, XOR-swizzled
  __shared__ __align__(16) unsigned short Bs[2][FOUTC * BK];   // 2 x 32 KB, XOR-swizzled

  const int t = threadIdx.x, wid = t >> 6, l = t & 63;
  const int bid = blockIdx.x;
  const int m = bid >> 2, ks = bid & 3;      // XCD x sees ks = x&3 only -> 1MB B slice/XCD L2
  const int bm0 = m * BM;
  const size_t k0 = (size_t)ks * KLOC;

  // A staging: thread t -> row ar = t>>3 (64 rows), float4-cols (t&7) and (t&7)+8
  const int ar = t >> 3, ac = t & 7;
  const float4* arow = reinterpret_cast<const float4*>(adj + (size_t)(bm0 + ar) * NROW + k0) + ac;
  const unsigned awoff0 = (unsigned)(ar * 128 + ((ac * 8) ^ ((ar & 7) << 4)));
  const unsigned awoff1 = (unsigned)(ar * 128 + ((ac * 8 + 64) ^ ((ar & 7) << 4)));

  // B staging via global_load_lds: lane l -> row c*8+(l>>3), pre-swizzled source kbyte
  const int bn = l >> 3;
  const unsigned bks = (unsigned)(((l & 7) * 16) ^ (bn << 4));

  f32x4 acc[2][4] = {};

  const int wm = wid >> 2, wn = wid & 3;     // 2M x 4N wave grid
  const int am0 = wm * 32, nb0 = wn * 64;
  const unsigned swz = (unsigned)((l & 7) << 4);
  const int fr = l & 15;
  const unsigned kb = (unsigned)((l >> 4) * 16);

  auto stageB = [&](int kt, int sl) {
#pragma unroll
    for (int i = 0; i < 4; ++i) {
      const int c = wid * 4 + i;
      const int n = c * 8 + bn;
      const unsigned short* src = s2T + (size_t)n * NROW + k0 + (size_t)kt * BK;
      __builtin_amdgcn_global_load_lds(
          (const __attribute__((address_space(1))) unsigned int*)((const char*)src + bks),
          (__attribute__((address_space(3))) unsigned int*)((char*)&Bs[sl][0] + c * 1024),
          16, 0, 0);
    }
  };
  auto writeA = [&](float4 v0, float4 v1, int sl) {
    ushort4 u0, u1;
    u0.x = f2bf(v0.x); u0.y = f2bf(v0.y); u0.z = f2bf(v0.z); u0.w = f2bf(v0.w);
    u1.x = f2bf(v1.x); u1.y = f2bf(v1.y); u1.z = f2bf(v1.z); u1.w = f2bf(v1.w);
    *reinterpret_cast<ushort4*>((char*)&As[sl][0] + awoff0) = u0;
    *reinterpret_cast<ushort4*>((char*)&As[sl][0] + awoff1) = u1;
  };
  auto compute = [&](int sl) {
    const char* Ab = (const char*)&As[sl][0];
    const char* Bb = (const char*)&Bs[sl][0];
#pragma unroll
    for (int kk = 0; kk < 2; ++kk) {
      const unsigned kx = ((unsigned)(kk * 64) + kb) ^ swz;
      bf16x8 a0 = *reinterpret_cast<const bf16x8*>(Ab + (am0 + fr) * 128 + kx);
      bf16x8 a1 = *reinterpret_cast<const bf16x8*>(Ab + (am0 + 16 + fr) * 128 + kx);
      bf16x8 b0 = *reinterpret_cast<const bf16x8*>(Bb + (nb0 + fr) * 128 + kx);
      bf16x8 b1 = *reinterpret_cast<const bf16x8*>(Bb + (nb0 + 16 + fr) * 128 + kx);
      bf16x8 b2 = *reinterpret_cast<const bf16x8*>(Bb + (nb0 + 32 + fr) * 128 + kx);
      bf16x8 b3 = *reinterpret_cast<const bf16x8*>(Bb + (nb0 + 48 + fr) * 128 + kx);
      acc[0][0] = __builtin_amdgcn_mfma_f32_16x16x32_bf16(a0, b0, acc[0][0], 0, 0, 0);
      acc[0][1] = __builtin_amdgcn_mfma_f32_16x16x32_bf16(a0, b1, acc[0][1], 0, 0, 0);
      acc[0][2] = __builtin_amdgcn_mfma_f32_16x16x32_bf16(a0, b2, acc[0][2], 0, 0, 0);
      acc[0][3] = __builtin_amdgcn_mfma_f32_16x16x32_bf16(a0, b3, acc[0][3], 0, 0, 0);
      acc[1][0] = __builtin_amdgcn_mfma_f32_16x16x32_bf16(a1, b0, acc[1][0], 0, 0, 0);
      acc[1][1] = __builtin_amdgcn_mfma_f32_16x16x32_bf16(a1, b1, acc[1][1], 0, 0, 0);
      acc[1][2] = __builtin_amdgcn_mfma_f32_16x16x32_bf16(a1, b2, acc[1][2], 0, 0, 0);
      acc[1][3] = __builtin_amdgcn_mfma_f32_16x16x32_bf16(a1, b3, acc[1][3], 0, 0, 0);
    }
  };

  // ---- prologue ----
  // issue order per wave: A(0)x2 | drain | B(0)x4, A(1)x2   -> 6 outstanding
  float4 aR0_0, aR0_1, aR1_0, aR1_1;
  {
    float4 v0 = arow[0], v1 = arow[8];
    asm volatile("s_waitcnt vmcnt(0)" ::: "memory");
    writeA(v0, v1, 0);
    stageB(0, 0);
    asm volatile("" ::: "memory");
    aR1_0 = arow[16]; aR1_1 = arow[24];
  }

  // ---- main loop: iter t: W1 vmcnt(2) -> B(t) landed (A(t+1) stays in flight);
  // issue B(t+1)x4 then A(t+2)x2; compute(t); W2 vmcnt(6) -> A(t+1) landed;
  // ds_write A(t+1) into slot (t+1)&1. Steady state: never drains below 2. ----
#define GITER(T, SC, SN, AW0, AW1, AN0, AN1)                                   \
  asm volatile("s_waitcnt vmcnt(2) lgkmcnt(0)\n\ts_barrier" ::: "memory");     \
  stageB((T) + 1, SN);                                                         \
  asm volatile("" ::: "memory");                                               \
  AN0 = arow[((T) + 2) * 16]; AN1 = arow[((T) + 2) * 16 + 8];                  \
  compute(SC);                                                                 \
  asm volatile("s_waitcnt vmcnt(6)" ::: "memory");                             \
  writeA(AW0, AW1, SN);

#pragma unroll 1
  for (int tt = 0; tt < NTL - 2; tt += 2) {
    GITER(tt + 0, 0, 1, aR1_0, aR1_1, aR0_0, aR0_1)
    GITER(tt + 1, 1, 0, aR0_0, aR0_1, aR1_0, aR1_1)
  }
#undef GITER
  // t = NTL-2 (slot 0): stage B(NTL-1), no A prefetch
  asm volatile("s_waitcnt vmcnt(2) lgkmcnt(0)\n\ts_barrier" ::: "memory");
  stageB(NTL - 1, 1);
  compute(0);
  asm volatile("s_waitcnt vmcnt(4)" ::: "memory");   // A(NTL-1) landed
  writeA(aR1_0, aR1_1, 1);
  // t = NTL-1 (slot 1)
  asm volatile("s_waitcnt vmcnt(0) lgkmcnt(0)\n\ts_barrier" ::: "memory");
  compute(1);

  // ---- epilogue: raw f32 partial store; C/D layout col = l&15, row = (l>>4)*4+q ----
  float* pout = part + (size_t)ks * NROW * FOUTC;
#pragma unroll
  for (int mm = 0; mm < 2; ++mm) {
#pragma unroll
    for (int n = 0; n < 4; ++n) {
#pragma unroll
      for (int q = 0; q < 4; ++q) {
        const int i = bm0 + am0 + mm * 16 + (l >> 4) * 4 + q;
        const int f = nb0 + n * 16 + fr;
        pout[(size_t)i * FOUTC + f] = acc[mm][n][q];
      }
    }
  }
}

// ---- kernel 4: out[i][f] = relu( (p0+p1+p2+p3 + s2R[i][f]) * D[i] + b[f] ) ----
__global__ __launch_bounds__(256) void combine_kernel(const float* __restrict__ part,
                                                      const unsigned short* __restrict__ s2R,
                                                      const float* __restrict__ D,
                                                      const float* __restrict__ bias,
                                                      float* __restrict__ out) {
  const int idx = blockIdx.x * 256 + threadIdx.x;   // one float4 per thread
  const int i = idx >> 6;
  const int f0 = (idx & 63) * 4;
  const size_t off = (size_t)i * FOUTC + f0;
  const size_t stride = (size_t)NROW * FOUTC;
  float4 p0 = *reinterpret_cast<const float4*>(part + off);
  float4 p1 = *reinterpret_cast<const float4*>(part + stride + off);
  float4 p2 = *reinterpret_cast<const float4*>(part + 2 * stride + off);
  float4 p3 = *reinterpret_cast<const float4*>(part + 3 * stride + off);
  ushort4 sv = *reinterpret_cast<const ushort4*>(s2R + off);
  float di = D[i];
  float4 bv = *reinterpret_cast<const float4*>(bias + f0);
  float4 o;
  o.x = fmaxf((p0.x + p1.x + p2.x + p3.x + bf2f(sv.x)) * di + bv.x, 0.f);
  o.y = fmaxf((p0.y + p1.y + p2.y + p3.y + bf2f(sv.y)) * di + bv.y, 0.f);
  o.z = fmaxf((p0.z + p1.z + p2.z + p3.z + bf2f(sv.z)) * di + bv.z, 0.f);
  o.w = fmaxf((p0.w + p1.w + p2.w + p3.w + bf2f(sv.w)) * di + bv.w, 0.f);
  *reinterpret_cast<float4*>(out + off) = o;
}

// ================= fallback path (round-3, used if ws too small) =============
__global__ __launch_bounds__(512) void gemm_fb(const float* __restrict__ adj,
                                               const unsigned short* __restrict__ s2T,
                                               const float* __restrict__ D,
                                               const float* __restrict__ bias,
                                               float* __restrict__ out) {
  __shared__ __align__(16) unsigned short As[3][32 * BK];
  __shared__ __align__(16) unsigned short Bs[3][FOUTC * BK];
  const int t = threadIdx.x, wid = t >> 6, l = t & 63;
  const int bm0 = blockIdx.x * 32;
  const int ar = t >> 4;
  const unsigned awoff = (unsigned)(ar * 128 + (((t & 15) * 8) ^ ((ar & 7) << 4)));
  const float4* arow = reinterpret_cast<const float4*>(adj + (size_t)(bm0 + ar) * NROW) + (t & 15);
  const int bn = l >> 3;
  const unsigned bks = (unsigned)(((l & 7) * 16) ^ (bn << 4));
  f32x4 acc[2][2] = {};
  const unsigned swz = (unsigned)((l & 7) << 4);
  const int fr = l & 15;
  const unsigned kb = (unsigned)((l >> 4) * 16);
  const int nb = wid * 32;
  const int NTF = NROW / BK;
  auto stageB = [&](int kt, int sl) {
#pragma unroll
    for (int i = 0; i < 4; ++i) {
      const int c = wid * 4 + i;
      const int n = c * 8 + bn;
      const unsigned short* src = s2T + (size_t)n * NROW + (size_t)kt * BK;
      __builtin_amdgcn_global_load_lds(
          (const __attribute__((address_space(1))) unsigned int*)((const char*)src + bks),
          (__attribute__((address_space(3))) unsigned int*)((char*)&Bs[sl][0] + c * 1024),
          16, 0, 0);
    }
  };
  auto writeA = [&](float4 av, int sl) {
    ushort4 ab;
    ab.x = f2bf(av.x); ab.y = f2bf(av.y); ab.z = f2bf(av.z); ab.w = f2bf(av.w);
    *reinterpret_cast<ushort4*>((char*)&As[sl][0] + awoff) = ab;
  };
  auto compute = [&](int sl) {
    const char* Ab = (const char*)&As[sl][0];
    const char* Bb = (const char*)&Bs[sl][0];
#pragma unroll
    for (int kk = 0; kk < 2; ++kk) {
      const unsigned kx = ((unsigned)(kk * 64) + kb) ^ swz;
      bf16x8 a0 = *reinterpret_cast<const bf16x8*>(Ab + fr * 128 + kx);
      bf16x8 a1 = *reinterpret_cast<const bf16x8*>(Ab + (fr + 16) * 128 + kx);
      bf16x8 b0 = *reinterpret_cast<const bf16x8*>(Bb + (nb + fr) * 128 + kx);
      bf16x8 b1 = *reinterpret_cast<const bf16x8*>(Bb + (nb + 16 + fr) * 128 + kx);
      acc[0][0] = __builtin_amdgcn_mfma_f32_16x16x32_bf16(a0, b0, acc[0][0], 0, 0, 0);
      acc[0][1] = __builtin_amdgcn_mfma_f32_16x16x32_bf16(a0, b1, acc[0][1], 0, 0, 0);
      acc[1][0] = __builtin_amdgcn_mfma_f32_16x16x32_bf16(a1, b0, acc[1][0], 0, 0, 0);
      acc[1][1] = __builtin_amdgcn_mfma_f32_16x16x32_bf16(a1, b1, acc[1][1], 0, 0, 0);
    }
  };
  float4 a0p, a1p, a2p;
  {
    float4 a0v = arow[0];
    asm volatile("" ::: "memory");
    stageB(0, 0);
    a1p = arow[16];
    asm volatile("" ::: "memory");
    stageB(1, 1);
    a2p = arow[32];
    asm volatile("s_waitcnt vmcnt(10)" ::: "memory");
    writeA(a0v, 0);
  }
#define PIPE_ITER(KT, S0, S1, S2, AW, AN)                                      \
  asm volatile("s_waitcnt vmcnt(5) lgkmcnt(0)\n\ts_barrier" ::: "memory");     \
  writeA(AW, S1);                                                              \
  stageB((KT) + 2, S2);                                                        \
  if ((KT) < NTF - 3) AN = arow[((KT) + 3) * 16];                              \
  compute(S0);
#pragma unroll 1
  for (int kt = 0; kt < NTF - 2; kt += 3) {
    PIPE_ITER(kt + 0, 0, 1, 2, a1p, a0p)
    PIPE_ITER(kt + 1, 1, 2, 0, a2p, a1p)
    PIPE_ITER(kt + 2, 2, 0, 1, a0p, a2p)
  }
#undef PIPE_ITER
  asm volatile("s_waitcnt vmcnt(4) lgkmcnt(0)\n\ts_barrier" ::: "memory");
  writeA(a1p, 1);
  compute(0);
  asm volatile("s_waitcnt vmcnt(0) lgkmcnt(0)\n\ts_barrier" ::: "memory");
  compute(1);
#pragma unroll
  for (int m = 0; m < 2; ++m) {
#pragma unroll
    for (int n = 0; n < 2; ++n) {
#pragma unroll
      for (int q = 0; q < 4; ++q) {
        const int i = bm0 + m * 16 + (l >> 4) * 4 + q;
        const int f = wid * 32 + n * 16 + fr;
        const float selfv = bf2f(s2T[(size_t)f * NROW + i]);
        float v = (acc[m][n][q] + selfv) * D[i] + bias[f];
        out[(size_t)i * FOUTC + f] = fmaxf(v, 0.0f);
      }
    }
  }
}

extern "C" void kernel_launch(void* const* d_in, const int* in_sizes, int n_in,
                              void* d_out, int out_size, void* d_ws, size_t ws_size,
                              hipStream_t stream) {
  const float* x   = (const float*)d_in[0];
  const float* adj = (const float*)d_in[1];
  const float* W   = (const float*)d_in[2];
  const float* b   = (const float*)d_in[3];
  float* out = (float*)d_out;

  char* wsb = (char*)d_ws;
  float* D            = (float*)wsb;                          // 32 KB
  unsigned short* s2T = (unsigned short*)(wsb + 32768);       // 4 MB  [f][j]
  unsigned short* s2R = (unsigned short*)(wsb + 32768 + (1u << 22));            // 4 MB [j][f]
  float* part         = (float*)(wsb + 32768 + (2u << 22));   // 32 MB (4 x 8 MB)

  const size_t need = 32768ull + (2ull << 22) + (size_t)KSPLIT * NROW * FOUTC * 4ull;
  rowsum_kernel<<<NROW / 4, 256, 0, stream>>>(adj, D);
  support_kernel<<<NROW / 32, 256, 0, stream>>>(x, W, D, s2T, s2R);
  if (ws_size >= need) {
    gcn_gemm_kernel<<<(NROW / BM) * KSPLIT, 512, 0, stream>>>(adj, s2T, part);
    combine_kernel<<<NROW * FOUTC / 1024, 256, 0, stream>>>(part, s2R, D, b, out);
  } else {
    gemm_fb<<<NROW / 32, 512, 0, stream>>>(adj, s2T, D, b, out);
  }
}